// Round 2
// baseline (251.176 us; speedup 1.0000x reference)
//
#include <hip/hip_runtime.h>
#include <hip/hip_bf16.h>
#include <stdint.h>

// Cheb graph conv: out[b,o,m,t] = sum_{k,n,c} T_k[n,m] x[b,c,n,t] Theta[k,c,o]
// Folded:  W[(o,m)][(c,n)] = sum_k T_k[n,m] Theta[k,c,o]
//          out_b (768x512) = W @ x_b (768x512) per batch, bf16 MFMA.
// R7: hoist the x transpose+bf16-cvt OUT of the GEMM (it was being redone 6x,
// with 16 scalar loads + 8 cvt + LDS round-trip + 2 barriers per kt = ~50
// instrs per 16 MFMAs -> latency/issue-bound at 93-106us vs 26us HBM floor).
//  - xprep: one pass x (b,k,t) fp32 -> xp (b,kt,t,k) bf16 (50MB, ~25-30us).
//  - gemm_direct: BOTH operands fragment-packed in global; inner loop is
//    8 coalesced b128 loads (contiguous 1KB/wave bursts, L2/L3-hot) + 16
//    MFMA. ZERO LDS, ZERO barriers, ZERO cvt. Waves fully independent.
//  - __launch_bounds__(256,4): ~106 VGPR -> 16 waves/CU for TLP latency hide.
//  - Fallback to proven R5 path if ws_size < 50MB.

#define NV 24
#define CIN 32
#define COUT 32
#define TDIM 512
#define BATCH 64
#define MDIM 768   // COUT*NV
#define KD 768     // CIN*NV
#define BM 128
#define BN 128
#define BK 32
#define NKT (KD / BK)    // 24
#define NTT (TDIM / BN)  // 4
#define NMT (MDIM / BM)  // 6
#define BLOB (BM * BK)   // 4096 shorts = 8 KB per (mt,kt) A blob

#define WP_SHORTS ((size_t)NMT * NKT * BLOB)                 // 589,824
#define XP_SHORTS ((size_t)BATCH * NKT * TDIM * BK)          // 25,165,824
#define WS_NEED ((WP_SHORTS + XP_SHORTS) * 2)                // ~49.1 MB

typedef __attribute__((ext_vector_type(8))) short short8v;  // 8 bf16
typedef __attribute__((ext_vector_type(4))) float float4v;  // 4 fp32 acc

__device__ inline unsigned short f2bf(float f) {
    unsigned int u = __float_as_uint(f);
    unsigned int r = (u + 0x7fffu + ((u >> 16) & 1u)) >> 16;
    return (unsigned short)r;
}

// ---------------------------------------------------------------------------
// prep_w: 64 blocks x 256 thr; writes Wp packed [mt][kt][128 m][32 k] bf16.
__global__ __launch_bounds__(256) void prep_w(const float* __restrict__ adj,
                                              const float* __restrict__ Theta,
                                              unsigned short* __restrict__ Wp) {
    __shared__ float adjS[NV * NV];
    __shared__ float disS[NV];
    __shared__ float LS[NV * NV];
    __shared__ float T2S[NV * NV];
    int tid = threadIdx.x;
    for (int e = tid; e < NV * NV; e += 256) adjS[e] = adj[e];
    __syncthreads();
    if (tid < NV) {
        float d = 0.f;
        for (int j = 0; j < NV; ++j) d += adjS[tid * NV + j];
        disS[tid] = (d > 0.f) ? rsqrtf(d) : 0.f;
    }
    __syncthreads();
    for (int e = tid; e < NV * NV; e += 256) {
        int i = e / NV, j = e % NV;
        LS[e] = disS[i] * adjS[j * NV + i] * disS[j];  // L = D^-1/2 A^T D^-1/2
    }
    __syncthreads();
    for (int e = tid; e < NV * NV; e += 256) {
        int i = e / NV, j = e % NV;
        float s = 0.f;
        for (int p = 0; p < NV; ++p) s += LS[i * NV + p] * LS[p * NV + j];
        T2S[e] = 2.f * s - (i == j ? 1.f : 0.f);
    }
    __syncthreads();
    int r0 = blockIdx.x * (MDIM / 64);  // 12 rows per block
    for (int e = tid; e < (MDIM / 64) * KD; e += 256) {
        int lr = e / KD, col = e % KD;
        int row = r0 + lr;
        int o = row / NV, m = row % NV;
        int c = col / NV, n = col % NV;
        float th0 = Theta[0 * CIN * COUT + c * COUT + o];
        float th1 = Theta[1 * CIN * COUT + c * COUT + o];
        float th2 = Theta[2 * CIN * COUT + c * COUT + o];
        float v = (n == m ? th0 : 0.f) + LS[n * NV + m] * th1 + T2S[n * NV + m] * th2;
        size_t idx = (((size_t)(row >> 7) * NKT + (col >> 5)) * BM + (row & 127)) * BK + (col & 31);
        Wp[idx] = f2bf(v);
    }
}

// ---------------------------------------------------------------------------
// xprep: x[b][k][t] fp32 -> xp[b][kt][t][kl] bf16.  grid 64*24*4 = 6144 blocks,
// each handles one (b, kt, 128t chunk): 32k x 128t tile.
#define TSTR 132  // LDS f32 row stride (128 + 4 pad)
__global__ __launch_bounds__(256) void xprep(const float* __restrict__ x,
                                             unsigned short* __restrict__ xp) {
    __shared__ float LS[BK * TSTR];  // 16.9 KB
    int bid = blockIdx.x;
    int tc = bid & 3;
    int kt = (bid >> 2) % NKT;
    int b = bid / (NKT * 4);
    int tid = threadIdx.x;
    int w = tid >> 6;
    int lane = tid & 63;
    int hi2 = lane >> 5;   // which of 2 rows this instr
    int tl = lane & 31;    // 16B chunk within 512B row

    const float* xs = x + ((size_t)b * KD + kt * BK) * TDIM + tc * 128;
    // phase 1: wave w loads rows k = w*8 .. w*8+7 (2 contiguous 512B rows per
    // instr), stages fp32 tile into LDS.
    float4 v[4];
#pragma unroll
    for (int c = 0; c < 4; ++c) {
        int k = w * 8 + c * 2 + hi2;
        v[c] = *(const float4*)(xs + (size_t)k * TDIM + tl * 4);
    }
#pragma unroll
    for (int c = 0; c < 4; ++c) {
        int k = w * 8 + c * 2 + hi2;
        *(float4*)(&LS[k * TSTR + tl * 4]) = v[c];
    }
    __syncthreads();
    // phase 2: thread (t = tid>>1, kh = tid&1) reads a 16-deep k column
    // (2 lanes/bank -> conflict-free), cvt to bf16, stores 32B to xp.
    int t = tid >> 1, kh = tid & 1;
    union { short8v s[2]; __hip_bfloat162 h[8]; } u;
#pragma unroll
    for (int p = 0; p < 8; ++p) {
        float f0 = LS[(kh * 16 + 2 * p) * TSTR + t];
        float f1 = LS[(kh * 16 + 2 * p + 1) * TSTR + t];
        u.h[p] = __float22bfloat162_rn({f0, f1});
    }
    unsigned short* xd = xp + (((size_t)b * NKT + kt) * TDIM + tc * 128 + t) * BK + kh * 16;
    *(short8v*)(xd) = u.s[0];
    *(short8v*)(xd + 8) = u.s[1];
}

// ---------------------------------------------------------------------------
// gemm_direct: out tile (128m x 128t); 4 waves (2x2 of 64x64). Both operands
// fragment-packed: per kt per wave, 4 A-frag + 4 B-frag b128 loads (each a
// contiguous 1KB wave burst) + 16 MFMA. No LDS, no barriers.
__global__ __launch_bounds__(256, 4) void gemm_direct(const unsigned short* __restrict__ Wp,
                                                      const unsigned short* __restrict__ xp,
                                                      float* __restrict__ out) {
    // XCD swizzle: the 6 mt-sharers of an x-slice land on one XCD window.
    int id = blockIdx.x;
    int hi = id / 48;
    int rem = id - hi * 48;
    int mt = rem >> 3;               // 0..5
    int g = hi * 8 + (rem & 7);      // 0..255
    int b = g >> 2;
    int tt = g & 3;

    int tid = threadIdx.x;
    int wave = tid >> 6;
    int lane = tid & 63;
    int quad = lane >> 4;
    int l16 = lane & 15;
    int wm = wave >> 1, wn = wave & 1;

    const short8v* Ap = (const short8v*)(Wp) + (size_t)mt * NKT * (BLOB / 8);
    const short8v* Bp = (const short8v*)(xp) + ((size_t)b * NKT * TDIM + (size_t)tt * BN) * (BK / 8);
    // fragment unit offsets (16B units): row r, k-quad q -> r*4 + q
    int afr = (wm * 64 + l16) * 4 + quad;  // + i*64 for i-th 16-row group
    int bfr = (wn * 64 + l16) * 4 + quad;  // + j*64

    const float4v zero4 = {0.f, 0.f, 0.f, 0.f};
    float4v acc[4][4];
#pragma unroll
    for (int i = 0; i < 4; ++i)
#pragma unroll
        for (int j = 0; j < 4; ++j) acc[i][j] = zero4;

    for (int kt = 0; kt < NKT; ++kt) {
        short8v a[4], bb[4];
#pragma unroll
        for (int i = 0; i < 4; ++i) a[i] = Ap[afr + i * 64];
#pragma unroll
        for (int j = 0; j < 4; ++j) bb[j] = Bp[bfr + j * 64];
#pragma unroll
        for (int i = 0; i < 4; ++i)
#pragma unroll
            for (int j = 0; j < 4; ++j)
                acc[i][j] = __builtin_amdgcn_mfma_f32_16x16x32_bf16(a[i], bb[j], acc[i][j], 0, 0, 0);
        Ap += BLOB / 8;          // 512 units
        Bp += TDIM * BK / 8;     // 2048 units
    }

    // C/D layout (m89): col = lane&15, row = quad*4 + reg
    float* outB = out + (size_t)b * MDIM * TDIM;
    int rbase = mt * BM + wm * 64;
    int cbase = tt * BN + wn * 64;
#pragma unroll
    for (int i = 0; i < 4; ++i) {
#pragma unroll
        for (int j = 0; j < 4; ++j) {
            int row0 = rbase + i * 16 + quad * 4;
            int col = cbase + j * 16 + l16;
#pragma unroll
            for (int r = 0; r < 4; ++r)
                outB[(size_t)(row0 + r) * TDIM + col] = acc[i][j][r];
        }
    }
}

// ---------------------------------------------------------------------------
// Fallback (R5, proven 93us/dispatch): fused transpose-in-loop GEMM, used
// only if ws_size can't hold xp.
#define BSTRIDE 40
__global__ __launch_bounds__(256, 4) void gemm_fallback(const unsigned short* __restrict__ Wp,
                                                        const float* __restrict__ x,
                                                        float* __restrict__ out) {
    __shared__ __attribute__((aligned(16))) unsigned short As[BM * BK];
    __shared__ __attribute__((aligned(16))) unsigned short Bs[BN * BSTRIDE];

    int id = blockIdx.x;
    int hi = id / 48;
    int rem = id - hi * 48;
    int mt = rem >> 3;
    int g = hi * 8 + (rem & 7);
    int b = g >> 2;
    int tt = g & 3;

    int tid = threadIdx.x;
    int wave = tid >> 6;
    int lane = tid & 63;
    int quad = lane >> 4;
    int l16 = lane & 15;
    int wm = wave >> 1, wn = wave & 1;
    int kq = wave;
    int tp = lane;

    const unsigned short* Ab = Wp + (size_t)mt * NKT * BLOB;
    const float* xb = x + (size_t)b * KD * TDIM + tt * BN;

    const float4v zero4 = {0.f, 0.f, 0.f, 0.f};
    float4v acc[4][4];
#pragma unroll
    for (int i = 0; i < 4; ++i)
#pragma unroll
        for (int j = 0; j < 4; ++j) acc[i][j] = zero4;

    uint4 Ar0, Ar1;
    float Xr[16];
    {
        const uint4* ap = (const uint4*)Ab;
        Ar0 = ap[tid];
        Ar1 = ap[tid + 256];
        const float* xr = xb + (size_t)(kq * 8) * TDIM;
#pragma unroll
        for (int kk = 0; kk < 8; ++kk) {
            Xr[kk] = xr[(size_t)kk * TDIM + tp];
            Xr[8 + kk] = xr[(size_t)kk * TDIM + tp + 64];
        }
    }

    for (int kt = 0; kt < NKT; ++kt) {
        union { short8v s; __hip_bfloat162 h[4]; } u0, u1;
#pragma unroll
        for (int i = 0; i < 4; ++i) {
            u0.h[i] = __float22bfloat162_rn({Xr[2 * i], Xr[2 * i + 1]});
            u1.h[i] = __float22bfloat162_rn({Xr[8 + 2 * i], Xr[8 + 2 * i + 1]});
        }
        uint4 a0 = Ar0, a1 = Ar1;

        __syncthreads();
        *(uint4*)(As + tid * 8) = a0;
        *(uint4*)(As + 2048 + tid * 8) = a1;
        *(short8v*)(Bs + tp * BSTRIDE + kq * 8) = u0.s;
        *(short8v*)(Bs + (tp + 64) * BSTRIDE + kq * 8) = u1.s;
        __syncthreads();

        if (kt + 1 < NKT) {
            const uint4* ap = (const uint4*)(Ab + (size_t)(kt + 1) * BLOB);
            Ar0 = ap[tid];
            Ar1 = ap[tid + 256];
            const float* xr = xb + (size_t)((kt + 1) * BK + kq * 8) * TDIM;
#pragma unroll
            for (int kk = 0; kk < 8; ++kk) {
                Xr[kk] = xr[(size_t)kk * TDIM + tp];
                Xr[8 + kk] = xr[(size_t)kk * TDIM + tp + 64];
            }
        }

        short8v a[4], bb[4];
#pragma unroll
        for (int i = 0; i < 4; ++i)
            a[i] = *(const short8v*)(As + (wm * 64 + i * 16 + l16) * BK + quad * 8);
#pragma unroll
        for (int j = 0; j < 4; ++j)
            bb[j] = *(const short8v*)(Bs + (wn * 64 + j * 16 + l16) * BSTRIDE + quad * 8);
#pragma unroll
        for (int i = 0; i < 4; ++i)
#pragma unroll
            for (int j = 0; j < 4; ++j)
                acc[i][j] = __builtin_amdgcn_mfma_f32_16x16x32_bf16(a[i], bb[j], acc[i][j], 0, 0, 0);
    }

    float* outB = out + (size_t)b * MDIM * TDIM;
    int rbase = mt * BM + wm * 64;
    int cbase = tt * BN + wn * 64;
#pragma unroll
    for (int i = 0; i < 4; ++i) {
#pragma unroll
        for (int j = 0; j < 4; ++j) {
            int row0 = rbase + i * 16 + quad * 4;
            int col = cbase + j * 16 + l16;
#pragma unroll
            for (int r = 0; r < 4; ++r)
                outB[(size_t)(row0 + r) * TDIM + col] = acc[i][j][r];
        }
    }
}

// ---------------------------------------------------------------------------
extern "C" void kernel_launch(void* const* d_in, const int* in_sizes, int n_in,
                              void* d_out, int out_size, void* d_ws, size_t ws_size,
                              hipStream_t stream) {
    const float* x = (const float*)d_in[0];      // (64,32,24,512) fp32
    const float* adj = (const float*)d_in[1];    // (24,24) fp32
    const float* Theta = (const float*)d_in[2];  // (3,32,32) fp32
    float* out = (float*)d_out;                  // (64,32,24,512) fp32

    unsigned short* Wp = (unsigned short*)d_ws;

    prep_w<<<64, 256, 0, stream>>>(adj, Theta, Wp);
    if (ws_size >= WS_NEED) {
        unsigned short* xp = Wp + WP_SHORTS;
        xprep<<<BATCH * NKT * 4, 256, 0, stream>>>(x, xp);
        gemm_direct<<<NMT * NTT * BATCH, 256, 0, stream>>>(Wp, xp, out);
    } else {
        gemm_fallback<<<NMT * NTT * BATCH, 256, 0, stream>>>(Wp, x, out);
    }
}

// Round 5
// 234.756 us; speedup vs baseline: 1.0699x; 1.0699x over previous
//
#include <hip/hip_runtime.h>
#include <hip/hip_bf16.h>
#include <stdint.h>

// Cheb graph conv: out[b,o,m,t] = sum_{k,n,c} T_k[n,m] x[b,c,n,t] Theta[k,c,o]
// Folded:  W[(o,m)][(c,n)] = sum_k T_k[n,m] Theta[k,c,o]
//          out_b (768x512) = W @ x_b (768x512) per batch, bf16 MFMA.
// R10 = R9 resubmitted verbatim (R9's bench died on container infra, kernel
// never measured). R9 = R8 with the stage-coverage bug fixed: phase-A loads
// 12 float2 per thread (192 rows x 32 float2 = 6144 = 512thr x 12), not 3.
// Design: single-pass, BM = full M = 768. Each block owns one (b, 64-t) slice:
//  - transpose+cvt its 768k x 64t fp32 slice into LDS bf16 ONCE,
//  - BARRIER-FREE main loop: per kt, 6 A-frag b128 loads direct from L2-hot
//    packed Wp + 4 conflict-free swizzled ds_reads + 24 MFMA, A fragments
//    double-buffered in registers (compile-time indices).
// HBM traffic = read x once (100MB) + write out once (100MB) -> 32us floor.
// LDS: Bs 96KB (bf16 [64t][96ku] XOR-swizzled) + LSf 49.5KB fp32 staging.

#define NV 24
#define CIN 32
#define COUT 32
#define TDIM 512
#define BATCH 64
#define MDIM 768   // COUT*NV
#define KD 768     // CIN*NV
#define BK 32
#define NKT (KD / BK)    // 24
#define BM 128           // Wp blob row-block (packing unchanged)
#define BLOB (BM * BK)   // 4096 shorts = 8 KB per (mtq,kt) A blob
#define BT 64            // t-cols per block
#define KUN (KD / 8)     // 96 k-units of 8 bf16
#define FSTR 66          // fp32 staging row stride (64 + 2 pad)

typedef __attribute__((ext_vector_type(8))) short short8v;  // 8 bf16
typedef __attribute__((ext_vector_type(4))) float float4v;  // 4 fp32 acc

__device__ inline unsigned short f2bf(float f) {
    unsigned int u = __float_as_uint(f);
    unsigned int r = (u + 0x7fffu + ((u >> 16) & 1u)) >> 16;
    return (unsigned short)r;
}

// ---------------------------------------------------------------------------
// prep_w: 64 blocks x 256 thr; writes Wp packed [mtq][kt][128 m][32 k] bf16.
__global__ __launch_bounds__(256) void prep_w(const float* __restrict__ adj,
                                              const float* __restrict__ Theta,
                                              unsigned short* __restrict__ Wp) {
    __shared__ float adjS[NV * NV];
    __shared__ float disS[NV];
    __shared__ float LS[NV * NV];
    __shared__ float T2S[NV * NV];
    int tid = threadIdx.x;
    for (int e = tid; e < NV * NV; e += 256) adjS[e] = adj[e];
    __syncthreads();
    if (tid < NV) {
        float d = 0.f;
        for (int j = 0; j < NV; ++j) d += adjS[tid * NV + j];
        disS[tid] = (d > 0.f) ? rsqrtf(d) : 0.f;
    }
    __syncthreads();
    for (int e = tid; e < NV * NV; e += 256) {
        int i = e / NV, j = e % NV;
        LS[e] = disS[i] * adjS[j * NV + i] * disS[j];  // L = D^-1/2 A^T D^-1/2
    }
    __syncthreads();
    for (int e = tid; e < NV * NV; e += 256) {
        int i = e / NV, j = e % NV;
        float s = 0.f;
        for (int p = 0; p < NV; ++p) s += LS[i * NV + p] * LS[p * NV + j];
        T2S[e] = 2.f * s - (i == j ? 1.f : 0.f);
    }
    __syncthreads();
    int r0 = blockIdx.x * (MDIM / 64);  // 12 rows per block
    for (int e = tid; e < (MDIM / 64) * KD; e += 256) {
        int lr = e / KD, col = e % KD;
        int row = r0 + lr;
        int o = row / NV, m = row % NV;
        int c = col / NV, n = col % NV;
        float th0 = Theta[0 * CIN * COUT + c * COUT + o];
        float th1 = Theta[1 * CIN * COUT + c * COUT + o];
        float th2 = Theta[2 * CIN * COUT + c * COUT + o];
        float v = (n == m ? th0 : 0.f) + LS[n * NV + m] * th1 + T2S[n * NV + m] * th2;
        size_t idx = (((size_t)(row >> 7) * NKT + (col >> 5)) * BM + (row & 127)) * BK + (col & 31);
        Wp[idx] = f2bf(v);
    }
}

// ---------------------------------------------------------------------------
// One kt step of the main loop. AC holds A fragments for KT; AN receives KT+1.
// All array indices compile-time (rule #20).
#define GSTEP(KT, AC, AN)                                                      \
    do {                                                                       \
        int kx = (((KT) * 4 + quad) ^ s7);                                     \
        short8v bb[4];                                                         \
        _Pragma("unroll")                                                      \
        for (int j = 0; j < 4; ++j) bb[j] = Bsv[tj[j] + kx];                   \
        if ((KT) + 1 < NKT) {                                                  \
            _Pragma("unroll")                                                  \
            for (int i = 0; i < 6; ++i) AN[i] = Apv[aoff[i] + ((KT) + 1) * 512]; \
        }                                                                      \
        _Pragma("unroll")                                                      \
        for (int i = 0; i < 6; ++i)                                            \
            _Pragma("unroll")                                                  \
            for (int j = 0; j < 4; ++j)                                        \
                acc[i][j] = __builtin_amdgcn_mfma_f32_16x16x32_bf16(           \
                    AC[i], bb[j], acc[i][j], 0, 0, 0);                         \
    } while (0)

// gemm_fullm: grid 512 = 64 b x 8 tt. 512 thr = 8 waves; wave w owns rows
// [w*96, w*96+96) x all 64 t. out tile per block = 768m x 64t.
__global__ __launch_bounds__(512, 2) void gemm_fullm(const unsigned short* __restrict__ Wp,
                                                     const float* __restrict__ x,
                                                     float* __restrict__ out) {
    // Bs: bf16 [t=64][ku=96] 16B units, XOR-swizzled (unit ^= t&7) -> 96 KB.
    __shared__ __attribute__((aligned(16))) unsigned short Bs[BT * KUN * 8];
    // LSf: fp32 transpose staging, one 192k x 64t chunk -> 49.5 KB.
    __shared__ float LSf[192 * FSTR];

    int id = blockIdx.x;
    int b = id >> 3;
    int tt = id & 7;
    int tid = threadIdx.x;
    int w = tid >> 6;          // wave 0..7
    int lane = tid & 63;
    int quad = lane >> 4;
    int l16 = lane & 15;
    int t = lane;              // stage phase-B: this thread's t column
    int s7 = l16 & 7;          // read-side swizzle key (t_j & 7 == l16 & 7)

    const float* xg = x + (size_t)b * KD * TDIM + (size_t)tt * BT;
    short8v* Bsv = (short8v*)Bs;

    // ---- stage: transpose 768k x 64t fp32 -> bf16 Bs, in 4 chunks of 192k ----
    // coverage: 192 rows x 32 float2 = 6144 = 512 threads x 12
    for (int kc = 0; kc < 4; ++kc) {
        float2 v[12];
#pragma unroll
        for (int p = 0; p < 12; ++p) {
            int idx = p * 512 + tid;
            int kloc = idx >> 5, c2 = idx & 31;
            v[p] = *(const float2*)(xg + (size_t)(kc * 192 + kloc) * TDIM + c2 * 2);
        }
#pragma unroll
        for (int p = 0; p < 12; ++p) {
            int idx = p * 512 + tid;
            int kloc = idx >> 5, c2 = idx & 31;
            *(float2*)(&LSf[kloc * FSTR + c2 * 2]) = v[p];
        }
        __syncthreads();
        // phase B: thread (t=lane, wave w) covers k-units w*3..w*3+2 of chunk
#pragma unroll
        for (int c = 0; c < 3; ++c) {
            union { short8v s; __hip_bfloat162 h[4]; } u;
#pragma unroll
            for (int p = 0; p < 4; ++p) {
                float f0 = LSf[(w * 24 + c * 8 + 2 * p) * FSTR + t];
                float f1 = LSf[(w * 24 + c * 8 + 2 * p + 1) * FSTR + t];
                u.h[p] = __float22bfloat162_rn({f0, f1});
            }
            int ku = kc * 24 + w * 3 + c;
            Bsv[t * KUN + (ku ^ (t & 7))] = u.s;
        }
        __syncthreads();  // LSf reads done before next chunk overwrites
    }

    // ---- A fragment global offsets (16B units into Wp) ----
    const short8v* Apv = (const short8v*)Wp;
    int aoff[6];
#pragma unroll
    for (int i = 0; i < 6; ++i) {
        int r = w * 96 + i * 16 + l16;
        aoff[i] = (r >> 7) * (NKT * 512) + (r & 127) * 4 + quad;
    }
    int tj[4];
#pragma unroll
    for (int j = 0; j < 4; ++j) tj[j] = (j * 16 + l16) * KUN;

    const float4v zero4 = {0.f, 0.f, 0.f, 0.f};
    float4v acc[6][4];
#pragma unroll
    for (int i = 0; i < 6; ++i)
#pragma unroll
        for (int j = 0; j < 4; ++j) acc[i][j] = zero4;

    short8v Aev[6], Aod[6];
#pragma unroll
    for (int i = 0; i < 6; ++i) Aev[i] = Apv[aoff[i]];  // kt = 0

    // ---- main loop: barrier-free, A reg-rotated, B from resident LDS ----
    for (int kt = 0; kt < NKT; kt += 2) {
        GSTEP(kt, Aev, Aod);
        GSTEP(kt + 1, Aod, Aev);
    }

    // ---- epilogue: C/D layout (m89): col = l16, row = quad*4 + reg ----
    float* outB = out + (size_t)b * MDIM * TDIM + (size_t)tt * BT;
    int rb0 = w * 96;
#pragma unroll
    for (int i = 0; i < 6; ++i) {
#pragma unroll
        for (int j = 0; j < 4; ++j) {
            int row0 = rb0 + i * 16 + quad * 4;
            int col = j * 16 + l16;
#pragma unroll
            for (int r = 0; r < 4; ++r)
                __builtin_nontemporal_store(acc[i][j][r],
                                            &outB[(size_t)(row0 + r) * TDIM + col]);
        }
    }
}

// ---------------------------------------------------------------------------
extern "C" void kernel_launch(void* const* d_in, const int* in_sizes, int n_in,
                              void* d_out, int out_size, void* d_ws, size_t ws_size,
                              hipStream_t stream) {
    const float* x = (const float*)d_in[0];      // (64,32,24,512) fp32
    const float* adj = (const float*)d_in[1];    // (24,24) fp32
    const float* Theta = (const float*)d_in[2];  // (3,32,32) fp32
    float* out = (float*)d_out;                  // (64,32,24,512) fp32

    unsigned short* Wp = (unsigned short*)d_ws;  // 1.125 MB packed W

    prep_w<<<64, 256, 0, stream>>>(adj, Theta, Wp);
    gemm_fullm<<<BATCH * (TDIM / BT), 512, 0, stream>>>(Wp, x, out);
}